// Round 1
// baseline (390.001 us; speedup 1.0000x reference)
//
#include <hip/hip_runtime.h>
#include <hip/hip_bf16.h>

#define NN 8192
#define FF 64
#define JSPLIT 16
#define JRANGE (NN / JSPLIT)    // 512 cols per block
#define JT 64                   // cols per iteration
#define NIT (JRANGE / JT)       // 8
#define PROW 66                 // partial row stride: H[0..63], l at [64]

// LDS (bytes): 4 B-buffers + factor window = 36864
#define B_OFF   0               // 4 x 8192: B tile 64 feats x 128 B (swizzled)
#define FAC_OFF 32768           // bfac 1024 | dfac 1024 | dup 2048
#define LDS_SZ  36864

typedef _Float16 half8 __attribute__((ext_vector_type(8)));
typedef _Float16 half4v __attribute__((ext_vector_type(4)));
typedef _Float16 half2v __attribute__((ext_vector_type(2)));
typedef float f32x4 __attribute__((ext_vector_type(4)));
typedef int i32x4 __attribute__((ext_vector_type(4)));

__device__ __forceinline__ void async16(const void* g, void* l)
{
    __builtin_amdgcn_global_load_lds(
        (const __attribute__((address_space(1))) unsigned int*)g,
        (__attribute__((address_space(3))) unsigned int*)l, 16, 0, 0);
}

// pack 8 adjacency ints (two i32x4) into an 8-bit mask
__device__ __forceinline__ unsigned pack8(i32x4 a, i32x4 b)
{
    unsigned by = 0;
    by |= (a[0] > 0) ? 1u   : 0u;
    by |= (a[1] > 0) ? 2u   : 0u;
    by |= (a[2] > 0) ? 4u   : 0u;
    by |= (a[3] > 0) ? 8u   : 0u;
    by |= (b[0] > 0) ? 16u  : 0u;
    by |= (b[1] > 0) ? 32u  : 0u;
    by |= (b[2] > 0) ? 64u  : 0u;
    by |= (b[3] > 0) ? 128u : 0u;
    return by;
}

// ---------------------------------------------------------------------------
// Kernel 1: Wh = inputs @ W; s, d; WhT fp16 (64 x NN); per-block max(d).
// ---------------------------------------------------------------------------
__global__ __launch_bounds__(256) void k_prep(const float* __restrict__ inp,
                                              const float* __restrict__ W,
                                              const float* __restrict__ a,
                                              _Float16* __restrict__ WhT,
                                              float* __restrict__ s,
                                              float* __restrict__ d,
                                              float* __restrict__ dmax_part)
{
    __shared__ float Wl[64][64];
    __shared__ float asrc[64], adst[64];
    __shared__ _Float16 tr[64][20];
    __shared__ float dmx[16];
    const int t = threadIdx.x;
    for (int idx = t; idx < 4096; idx += 256) Wl[idx >> 6][idx & 63] = W[idx];
    if (t < 64) { asrc[t] = a[t]; adst[t] = a[64 + t]; }
    __syncthreads();

    const int rowl = t >> 4;
    const int fg   = t & 15;
    const int row  = blockIdx.x * 16 + rowl;
    const float* ip = inp + (size_t)row * FF;

    float a0 = 0.f, a1 = 0.f, a2 = 0.f, a3 = 0.f;
    #pragma unroll
    for (int k4 = 0; k4 < 16; ++k4) {
        float4 x  = *(const float4*)(ip + k4 * 4);
        float4 w0 = *(const float4*)&Wl[k4 * 4 + 0][fg * 4];
        float4 w1 = *(const float4*)&Wl[k4 * 4 + 1][fg * 4];
        float4 w2 = *(const float4*)&Wl[k4 * 4 + 2][fg * 4];
        float4 w3 = *(const float4*)&Wl[k4 * 4 + 3][fg * 4];
        a0 += x.x * w0.x + x.y * w1.x + x.z * w2.x + x.w * w3.x;
        a1 += x.x * w0.y + x.y * w1.y + x.z * w2.y + x.w * w3.y;
        a2 += x.x * w0.z + x.y * w1.z + x.z * w2.z + x.w * w3.z;
        a3 += x.x * w0.w + x.y * w1.w + x.z * w2.w + x.w * w3.w;
    }

    float sp = a0 * asrc[fg*4] + a1 * asrc[fg*4+1] + a2 * asrc[fg*4+2] + a3 * asrc[fg*4+3];
    float dp = a0 * adst[fg*4] + a1 * adst[fg*4+1] + a2 * adst[fg*4+2] + a3 * adst[fg*4+3];
    #pragma unroll
    for (int msk = 1; msk < 16; msk <<= 1) {
        sp += __shfl_xor(sp, msk);
        dp += __shfl_xor(dp, msk);
    }
    if (fg == 0) { s[row] = sp; d[row] = dp; dmx[rowl] = dp; }

    tr[fg * 4 + 0][rowl] = (_Float16)a0;
    tr[fg * 4 + 1][rowl] = (_Float16)a1;
    tr[fg * 4 + 2][rowl] = (_Float16)a2;
    tr[fg * 4 + 3][rowl] = (_Float16)a3;
    __syncthreads();
    {
        const int f = t >> 2, seg = t & 3;
        *(half4v*)(WhT + (size_t)f * NN + blockIdx.x * 16 + seg * 4) =
            *(const half4v*)&tr[f][seg * 4];
    }
    if (t == 0) {
        float mm = dmx[0];
        #pragma unroll
        for (int i = 1; i < 16; ++i) mm = fmaxf(mm, dmx[i]);
        dmax_part[blockIdx.x] = mm;
    }
}

// ---------------------------------------------------------------------------
// Kernel 2: dmax; separable softmax factors (all <= 1, fp16-safe).
// ---------------------------------------------------------------------------
__global__ __launch_bounds__(256) void k_vec(const float* __restrict__ s,
                                             const float* __restrict__ d,
                                             const float* __restrict__ dmax_part,
                                             _Float16* __restrict__ afac,
                                             _Float16* __restrict__ cfac,
                                             _Float16* __restrict__ bfac,
                                             _Float16* __restrict__ dfac)
{
    __shared__ float red[256];
    const int t = threadIdx.x;
    float m = fmaxf(dmax_part[t], dmax_part[t + 256]);
    red[t] = m;
    __syncthreads();
    for (int off = 128; off > 0; off >>= 1) {
        if (t < off) red[t] = fmaxf(red[t], red[t + off]);
        __syncthreads();
    }
    const float dmax = red[0];
    const int row = blockIdx.x * 256 + t;
    const float x = s[row] + dmax;
    const float c = fmaxf(x, 0.2f * x);
    afac[row] = (_Float16)__expf(x - c);
    cfac[row] = (_Float16)__expf(0.2f * x - c);
    const float y = d[row] - dmax;
    bfac[row] = (_Float16)__expf(y);
    dfac[row] = (_Float16)__expf(0.2f * y);
}

// ---------------------------------------------------------------------------
// Kernel 3 (main, FUSED): 1024 blocks = 64 row-tiles(128 rows) x 16 j-splits.
// adj is read DIRECTLY per iteration (no k_pack / mask2 round trip): each
// lane loads the 32 adj ints it owns (8 x i32x4; the a/b + cc pairs cover
// full 128-B lines across the 4 g-lanes) and packs mask bytes in VALU.
// Issue order per iter: adj loads FIRST, then stageB(it+2) DMA, separated by
// sched_barrier(0) so the compiler's adj-consume wait is vmcnt(2), keeping
// the newest B-tile DMA pair in flight. Everything else unchanged.
// ---------------------------------------------------------------------------
__global__ __launch_bounds__(256, 4) void k_main(const int* __restrict__ adj,
                                                 const _Float16* __restrict__ WhT,
                                                 const _Float16* __restrict__ afac,
                                                 const _Float16* __restrict__ cfac,
                                                 const _Float16* __restrict__ bfac,
                                                 const _Float16* __restrict__ dfac,
                                                 float* __restrict__ part)
{
    __shared__ __align__(16) unsigned char sm[LDS_SZ];

    const int tid  = threadIdx.x;
    const int wv   = tid >> 6;
    const int lane = tid & 63;
    const int mrow = lane & 15;
    const int g    = lane >> 4;
    const int rt   = blockIdx.x & 63;
    const int js   = blockIdx.x >> 6;
    const int i0   = rt * 128;
    const int j0base = js * JRANGE;
    const int arow0 = i0 + wv * 32 + mrow;   // row-group 0
    const int arow1 = arow0 + 16;            // row-group 1

    // per-lane adj base pointers (cols j0base + g*8 ...)
    const int* ap0 = adj + (size_t)arow0 * NN + j0base + g * 8;
    const int* ap1 = adj + (size_t)arow1 * NN + j0base + g * 8;

    // ---- per-row factors (packed pairs)
    half2v a2[2], c2[2];
    {
        union { _Float16 h[2]; half2v v; } u;
        u.h[0] = afac[arow0]; u.h[1] = u.h[0]; a2[0] = u.v;
        u.h[0] = cfac[arow0]; u.h[1] = u.h[0]; c2[0] = u.v;
        u.h[0] = afac[arow1]; u.h[1] = u.h[0]; a2[1] = u.v;
        u.h[0] = cfac[arow1]; u.h[1] = u.h[0]; c2[1] = u.v;
    }

    f32x4 acc[2][5];
    #pragma unroll
    for (int r = 0; r < 2; ++r)
        #pragma unroll
        for (int n = 0; n < 5; ++n) acc[r][n] = (f32x4){0.f, 0.f, 0.f, 0.f};

    // stage B tile for iter it into buffer it&3 (2 async16/wave, swizzled)
    auto stageB = [&](int it) {
        const int j0 = j0base + it * JT;
        unsigned char* base = &sm[B_OFF + (it & 3) * 8192];
        #pragma unroll
        for (int qq = 0; qq < 2; ++qq) {
            const int q  = wv * 2 + qq;
            const int f  = q * 8 + (lane >> 3);
            const int sw = (lane & 7) ^ (lane >> 3);
            async16(WhT + (size_t)f * NN + j0 + sw * 8,
                    base + q * 1024 + lane * 16);
        }
    };

    // ---- prologue: factor window (1 async16/wave, uniform count) + tiles 0,1
    {
        const _Float16* fsrc = (wv == 0) ? (bfac + j0base + lane * 8)
                             : (wv == 1) ? (dfac + j0base + lane * 8)
                             : (wv == 2) ? (bfac + j0base + lane * 8)
                                         : (dfac + j0base + lane * 8);
        const int dst = (wv == 0) ? 0 : (wv == 1) ? 1024 : 2048 + (wv - 2) * 1024;
        async16(fsrc, &sm[FAC_OFF + dst + lane * 16]);
    }
    stageB(0);
    stageB(1);

    const half8 ones = {(_Float16)1.f, (_Float16)1.f, (_Float16)1.f, (_Float16)1.f,
                        (_Float16)1.f, (_Float16)1.f, (_Float16)1.f, (_Float16)1.f};
    const int r7 = mrow & 7;
    const int qh = mrow >> 3;

    #pragma unroll
    for (int it = 0; it < NIT; ++it) {
        if (it < NIT - 1)
            asm volatile("s_waitcnt vmcnt(2)" ::: "memory");  // tile(it) landed
        else
            asm volatile("s_waitcnt vmcnt(0)" ::: "memory");
        __builtin_amdgcn_s_barrier();
        asm volatile("" ::: "memory");

        // ---- adj tile loads for THIS iter (8 x i32x4 per lane), issued
        //      BEFORE the next-tile DMA so their consume-wait is vmcnt(2).
        i32x4 q00a = __builtin_nontemporal_load((const i32x4*)(ap0 + it * 64));
        i32x4 q00b = __builtin_nontemporal_load((const i32x4*)(ap0 + it * 64 + 4));
        i32x4 q01a = __builtin_nontemporal_load((const i32x4*)(ap0 + it * 64 + 32));
        i32x4 q01b = __builtin_nontemporal_load((const i32x4*)(ap0 + it * 64 + 36));
        i32x4 q10a = __builtin_nontemporal_load((const i32x4*)(ap1 + it * 64));
        i32x4 q10b = __builtin_nontemporal_load((const i32x4*)(ap1 + it * 64 + 4));
        i32x4 q11a = __builtin_nontemporal_load((const i32x4*)(ap1 + it * 64 + 32));
        i32x4 q11b = __builtin_nontemporal_load((const i32x4*)(ap1 + it * 64 + 36));
        __builtin_amdgcn_sched_barrier(0);

        if (it + 2 < NIT) stageB(it + 2);                     // prefetch DMA
        __builtin_amdgcn_sched_barrier(0);

        unsigned btl[2][2];
        btl[0][0] = pack8(q00a, q00b);
        btl[0][1] = pack8(q01a, q01b);
        btl[1][0] = pack8(q10a, q10b);
        btl[1][1] = pack8(q11a, q11b);

        const unsigned char* bb = &sm[B_OFF + (it & 3) * 8192];

        #pragma unroll
        for (int cc = 0; cc < 2; ++cc) {
            const int colb = (it * 64 + cc * 32 + g * 8) * 2;
            uint4 bv4 = *(const uint4*)&sm[FAC_OFF + colb];
            uint4 dv4 = *(const uint4*)&sm[FAC_OFF + 1024 + colb];

            union { unsigned u[4]; half8 h; } af[2];
            #pragma unroll
            for (int r = 0; r < 2; ++r) {
                const unsigned bt = btl[r][cc];
                #pragma unroll
                for (int k = 0; k < 4; ++k) {
                    union { unsigned u; half2v v; } b2, d2, pm;
                    b2.u = (&bv4.x)[k];
                    d2.u = (&dv4.x)[k];
                    pm.v = __builtin_elementwise_max(a2[r] * b2.v, c2[r] * d2.v);
                    const unsigned lo = ((bt >> (2 * k)) & 1u) * 0xFFFFu;
                    const unsigned hi = ((bt >> (2 * k + 1)) & 1u) * 0xFFFF0000u;
                    af[r].u[k] = pm.u & (lo | hi);
                }
            }

            #pragma unroll
            for (int n = 0; n < 4; ++n) {
                const int q = n * 2 + qh;
                half8 B = *(const half8*)&bb[q * 1024 + r7 * 128 +
                                             (((cc * 4 + g) ^ r7) * 16)];
                acc[0][n] = __builtin_amdgcn_mfma_f32_16x16x32_f16(af[0].h, B, acc[0][n], 0, 0, 0);
                acc[1][n] = __builtin_amdgcn_mfma_f32_16x16x32_f16(af[1].h, B, acc[1][n], 0, 0, 0);
            }
            acc[0][4] = __builtin_amdgcn_mfma_f32_16x16x32_f16(af[0].h, ones, acc[0][4], 0, 0, 0);
            acc[1][4] = __builtin_amdgcn_mfma_f32_16x16x32_f16(af[1].h, ones, acc[1][4], 0, 0, 0);
        }
    }

    // ---- epilogue: rows i = wv*32 + r*16 + (g*4+reg); col = n*16+mrow ----
    float* pb = part + (size_t)blockIdx.x * (128 * PROW) + wv * 32 * PROW;
    #pragma unroll
    for (int r = 0; r < 2; ++r) {
        #pragma unroll
        for (int n = 0; n < 4; ++n)
            #pragma unroll
            for (int reg = 0; reg < 4; ++reg)
                pb[(r * 16 + g * 4 + reg) * PROW + n * 16 + mrow] = acc[r][n][reg];
        if (mrow == 0) {
            #pragma unroll
            for (int reg = 0; reg < 4; ++reg)
                pb[(r * 16 + g * 4 + reg) * PROW + 64] = acc[r][4][reg];
        }
    }
}

// ---------------------------------------------------------------------------
// Kernel 4: combine 16 j-split partials, divide by l, ELU, write out.
// ---------------------------------------------------------------------------
__global__ __launch_bounds__(256) void k_reduce(const float* __restrict__ part,
                                                float* __restrict__ out)
{
    const int rb  = blockIdx.x;
    const int col = threadIdx.x & 63;
    const int r0  = threadIdx.x >> 6;
    #pragma unroll
    for (int rr = 0; rr < 4; ++rr) {
        const int r   = rb * 16 + r0 * 4 + rr;
        const int rtr = r >> 7;
        const int rl  = r & 127;
        float h = 0.f, l = 0.f;
        #pragma unroll
        for (int js = 0; js < JSPLIT; ++js) {
            const float* pbase =
                part + ((size_t)(js * 64 + rtr) * 128 + rl) * PROW;
            h += pbase[col];
            l += pbase[64];
        }
        float v = h / l;
        out[(size_t)r * FF + col] = (v > 0.f) ? v : (__expf(v) - 1.0f);
    }
}

extern "C" void kernel_launch(void* const* d_in, const int* in_sizes, int n_in,
                              void* d_out, int out_size, void* d_ws, size_t ws_size,
                              hipStream_t stream)
{
    const float* inp = (const float*)d_in[0];
    const int*   adj = (const int*)d_in[1];
    const float* W   = (const float*)d_in[2];
    const float* a   = (const float*)d_in[3];
    float* out = (float*)d_out;

    char* ws = (char*)d_ws;
    _Float16* WhT = (_Float16*)ws;                          // 80*NN*2 reserved
    float* s    = (float*)(ws + (size_t)80 * NN * 2);
    float* d    = s + NN;
    float* dmp  = d + NN;
    _Float16* afac = (_Float16*)(dmp + 512);
    _Float16* cfac = afac + NN;
    _Float16* bfac = cfac + NN;
    _Float16* dfac = bfac + NN;
    float* part = (float*)(dfac + NN);                      // 1024*128*66*4 = 34.6 MB

    k_prep  <<<NN / 16, 256, 0, stream>>>(inp, W, a, WhT, s, d, dmp);
    k_vec   <<<NN / 256, 256, 0, stream>>>(s, d, dmp, afac, cfac, bfac, dfac);
    k_main  <<<64 * JSPLIT, 256, 0, stream>>>(adj, WhT, afac, cfac, bfac, dfac, part);
    k_reduce<<<NN / 16, 256, 0, stream>>>(part, out);
}